// Round 6
// baseline (195.956 us; speedup 1.0000x reference)
//
#include <hip/hip_runtime.h>

#define H     128
#define NP    512
#define NVOX  50000
#define NEDGE 800000
#define EPV   16
#define SLOPE 0.01f
#define GR    16                          // voxel rows per k_mainX block
#define NBLK  3125                        // NVOX/GR exactly (no tail!)
#define STRH  136                         // padded f16 LDS stride (halves)
#define VSTR  132                         // padded f32 LDS stride (floats)
#define C1    2.8853900817779268f         // 2*log2(e)
#define LOG2E 1.4426950408889634f
#define ABLK  3125                        // k_out part-A blocks

#define EXP2(x) __builtin_amdgcn_exp2f(x)
#define LOG2(x) __builtin_amdgcn_logf(x)
#define RCP(x)  __builtin_amdgcn_rcpf(x)

typedef _Float16 h16;
typedef __attribute__((ext_vector_type(4))) _Float16 h16x4;
typedef __attribute__((ext_vector_type(8))) _Float16 h16x8;
typedef __attribute__((ext_vector_type(4))) float    f32x4;

// DPP butterfly add: 0xB1=quad_perm[1,0,3,2] (xor1), 0x4E=quad_perm[2,3,0,1]
// (xor2), 0x141=row_half_mirror (xor4 once quads uniform), 0x140=row_mirror
// (xor8 once 8-groups uniform). Pure VALU, short dependency chain.
template <int CTRL>
__device__ __forceinline__ float dpp_add(float x) {
    union { float f; int i; } u, r;
    u.f = x;
    r.i = __builtin_amdgcn_update_dpp(0, u.i, CTRL, 0xf, 0xf, true);
    return x + r.f;
}

// ==== blocks [0,NP): xp' = (x@Wp+bp)*C1 ; blocks [NP,NP+128): W split ====
__global__ __launch_bounds__(256) void k_pre(const float* __restrict__ x,
                                             const float* __restrict__ Wp,
                                             const float* __restrict__ bp,
                                             const float* __restrict__ Wv,
                                             const float* __restrict__ Wm1,
                                             float* __restrict__ xpout,
                                             h16* __restrict__ WvThi,
                                             h16* __restrict__ WvTlo,
                                             h16* __restrict__ Wm1T) {
    __shared__ float part[H];
    int bid = blockIdx.x;
    int tid = threadIdx.x;
    if (bid < NP) {
        int row = bid;
        int col = tid & 127;
        int kh  = tid >> 7;
        int kbase = kh * 64;
        const float* xr = x + (size_t)row * H;
        float acc = 0.f;
#pragma unroll 8
        for (int k = 0; k < 64; ++k)
            acc = fmaf(xr[kbase + k], Wp[(size_t)(kbase + k) * H + col], acc);
        if (kh == 1) part[col] = acc;
        __syncthreads();
        if (kh == 0) xpout[(size_t)row * H + col] = (acc + part[col] + bp[col]) * C1;
    } else {
        int idx = (bid - NP) * 256 + tid;
        if (idx < 16384) {
            int k = idx >> 7, n = idx & 127;
            float w = Wv[idx];
            h16 hi = (h16)w;
            WvThi[n * H + k] = hi;
            WvTlo[n * H + k] = (h16)(w - (float)hi);
        } else {
            int j = idx - 16384;
            int k = j >> 7, n = j & 127;
            Wm1T[n * H + k] = (h16)Wm1[j];
        }
    }
}

// ======= fused: vv GEMM (LDS-only), mask, per-edge p (prefetched gathers),
//         sump = sum p*x[src], per-block psum partial =======
// GR=16: 3125 blocks (12.2/CU grid pressure, backfill), LDS 11264B.
// launch_bounds (256,4): VGPR budget 128 -> compiler takes ~60, NO SPILLS.
// (R1 ran this structure at (256,8): VGPR forced to 32, ~450B/lane scratch
// spill, FETCH 42MB. R5's occupancy math shows residency ~2.5 blk/CU is the
// limiter at GR=32 -> more, smaller blocks + backfill is the occupancy lever.)
__global__ __launch_bounds__(256, 4) void k_mainX(
    const float* __restrict__ v,   const float* __restrict__ x,
    const float* __restrict__ bv,  const float* __restrict__ bm1,
    const float* __restrict__ Wm2, const float* __restrict__ bm2,
    const h16* __restrict__ WvThi, const h16* __restrict__ WvTlo,
    const h16* __restrict__ Wm1T,
    const float* __restrict__ xp,  const int* __restrict__ cei,
    const float* __restrict__ theta, const float* __restrict__ gum,
    float* __restrict__ mask_out, float* __restrict__ pout,
    float* __restrict__ sump,     float* __restrict__ partial)
{
    __shared__ __align__(16) char ldsbuf[2 * GR * STRH * 2];  // 8704 B
    h16*   vh = (h16*)ldsbuf;            // [GR][STRH]
    h16*   vl = vh + GR * STRH;
    float* vt = (float*)ldsbuf;          // [GR][VSTR] f32 vv tile (reuse, 8448B)
    __shared__ int   ceit[EPV * GR];     // [t*GR+c]
    __shared__ float gumt[EPV * GR];     // pre-transformed: exp(gumbel)
    __shared__ float pmbuf[4][GR];
    __shared__ float psums[4];

    int tid  = threadIdx.x;
    int base = blockIdx.x * GR;          // NVOX = GR*NBLK exactly: no tail

    // ---- stage v tile (f16 hi/lo split) + cei/gum tiles ----
#pragma unroll
    for (int i = 0; i < 2; ++i) {
        int f  = i * 256 + tid;          // 512 float4 slots
        int r  = f >> 5, c4 = f & 31;
        float4 val = *(const float4*)&v[(size_t)(base + r) * H + c4 * 4];
        h16x4 hi, lo;
        hi.x = (h16)val.x; lo.x = (h16)(val.x - (float)hi.x);
        hi.y = (h16)val.y; lo.y = (h16)(val.y - (float)hi.y);
        hi.z = (h16)val.z; lo.z = (h16)(val.z - (float)hi.z);
        hi.w = (h16)val.w; lo.w = (h16)(val.w - (float)hi.w);
        *(h16x4*)&vh[r * STRH + c4 * 4] = hi;
        *(h16x4*)&vl[r * STRH + c4 * 4] = lo;
    }
    {
        int t = tid >> 4, c = tid & 15;  // 256 slots, 1 per thread
        int e = base + c + t * NVOX;
        ceit[tid] = cei[e];
        gumt[tid] = -LOG2E * RCP(LOG2(gum[e]));   // exp(gumbel) hoisted
    }
    __syncthreads();

    // ---- dual GEMM via MFMA 16x16x32 f16 (split hi/lo for Wv), M=16 ----
    int wave = tid >> 6, lane = tid & 63;
    int m16 = lane & 15, quad = lane >> 4;
    int cb = wave * 32;

    f32x4 aV[2], aM[2];
    aV[0] = (f32x4)0.f; aV[1] = (f32x4)0.f;
    aM[0] = (f32x4)0.f; aM[1] = (f32x4)0.f;

#pragma unroll
    for (int kc = 0; kc < 4; ++kc) {
        int kofs = kc * 32 + quad * 8;
        h16x8 ah = *(const h16x8*)&vh[m16 * STRH + kofs];
        h16x8 al = *(const h16x8*)&vl[m16 * STRH + kofs];
#pragma unroll
        for (int ct = 0; ct < 2; ++ct) {
            int n = cb + ct * 16 + m16;
            h16x8 bh = *(const h16x8*)&WvThi[n * H + kofs];
            h16x8 bl = *(const h16x8*)&WvTlo[n * H + kofs];
            h16x8 bm = *(const h16x8*)&Wm1T[n * H + kofs];
            aV[ct] = __builtin_amdgcn_mfma_f32_16x16x32_f16(ah, bh, aV[ct], 0, 0, 0);
            aV[ct] = __builtin_amdgcn_mfma_f32_16x16x32_f16(al, bh, aV[ct], 0, 0, 0);
            aV[ct] = __builtin_amdgcn_mfma_f32_16x16x32_f16(ah, bl, aV[ct], 0, 0, 0);
            aM[ct] = __builtin_amdgcn_mfma_f32_16x16x32_f16(ah, bm, aM[ct], 0, 0, 0);
        }
    }
    __syncthreads();                     // vh/vl fully consumed

    // ---- write vv tile (prescaled by C1) to LDS + mask partials ----
    float pml[4] = {0.f, 0.f, 0.f, 0.f};
#pragma unroll
    for (int ct = 0; ct < 2; ++ct) {
        int col = cb + ct * 16 + m16;
        float bvc = bv[col], bmc = bm1[col], w2c = Wm2[col];
#pragma unroll
        for (int reg = 0; reg < 4; ++reg) {
            int row = quad * 4 + reg;
            vt[row * VSTR + col] = (aV[ct][reg] + bvc) * C1;
            float m = aM[ct][reg] + bmc;
            m = (m >= 0.f) ? m : SLOPE * m;
            pml[reg] = fmaf(m, w2c, pml[reg]);
        }
    }
#pragma unroll
    for (int reg = 0; reg < 4; ++reg) {  // 16-lane (m16) sum, pure-VALU DPP
        pml[reg] = dpp_add<0xB1>(pml[reg]);
        pml[reg] = dpp_add<0x4E>(pml[reg]);
        pml[reg] = dpp_add<0x141>(pml[reg]);
        pml[reg] = dpp_add<0x140>(pml[reg]);
    }
    if (m16 == 0) {
#pragma unroll
        for (int reg = 0; reg < 4; ++reg)
            pmbuf[wave][quad * 4 + reg] = pml[reg];
    }
    __syncthreads();                     // vt + pmbuf visible
    if (tid < GR) {
        float s = pmbuf[0][tid] + pmbuf[1][tid] + pmbuf[2][tid] + pmbuf[3][tid]
                + bm2[0];
        mask_out[base + tid] = RCP(1.f + EXP2(-s * LOG2E));
    }

    // ---- edges: 16 lanes/edge, group g owns voxel base+g, prefetched xp rows ----
    int g = tid >> 4, lk = tid & 15;
    int vox = base + g;
    float th2[8], thsum;
    {
        float4 ta = *(const float4*)&theta[lk * 4];
        float4 tb = *(const float4*)&theta[(lk + 16) * 4];
        th2[0] = -2.f * LOG2E * ta.x; th2[1] = -2.f * LOG2E * ta.y;
        th2[2] = -2.f * LOG2E * ta.z; th2[3] = -2.f * LOG2E * ta.w;
        th2[4] = -2.f * LOG2E * tb.x; th2[5] = -2.f * LOG2E * tb.y;
        th2[6] = -2.f * LOG2E * tb.z; th2[7] = -2.f * LOG2E * tb.w;
        thsum = LOG2E * (ta.x + ta.y + ta.z + ta.w + tb.x + tb.y + tb.z + tb.w);
    }
    const float* vr = &vt[g * VSTR];
    float4 b0 = *(const float4*)&vr[lk * 4];
    float4 b1 = *(const float4*)&vr[(lk + 16) * 4];

    float4 s0 = make_float4(0.f, 0.f, 0.f, 0.f), s1 = s0;
    float psum = 0.f, pmax = -1.f;
    int   pidx = 0;

    int srcC = ceit[g];                  // t = 0
    const float4* xr0 = (const float4*)(xp + (size_t)srcC * H);
    float4 a0 = xr0[lk], a1 = xr0[lk + 16];

    for (int t = 0; t < EPV; ++t) {
        // prefetch next xp row (the only latency-exposed gather)
        float4 n0, n1;
        int srcN;
        if (t < EPV - 1) {
            srcN = ceit[(t + 1) * GR + g];
            const float4* xrN = (const float4*)(xp + (size_t)srcN * H);
            n0 = xrN[lk]; n1 = xrN[lk + 16];
        } else {
            srcN = srcC; n0 = a0; n1 = a1;
        }
        // x row: first use is far away (behind trans chain)
        const float4* xo = (const float4*)(x + (size_t)srcC * H);
        float4 c0 = xo[lk], c1 = xo[lk + 16];
        float wvt = gumt[t * GR + g];    // exp(gumbel), pre-transformed

        float acc0 = thsum, acc1 = 0.f;
        acc0 = fmaf(th2[0], RCP(EXP2(a0.x + b0.x) + 1.f), acc0);
        acc1 = fmaf(th2[1], RCP(EXP2(a0.y + b0.y) + 1.f), acc1);
        acc0 = fmaf(th2[2], RCP(EXP2(a0.z + b0.z) + 1.f), acc0);
        acc1 = fmaf(th2[3], RCP(EXP2(a0.w + b0.w) + 1.f), acc1);
        acc0 = fmaf(th2[4], RCP(EXP2(a1.x + b1.x) + 1.f), acc0);
        acc1 = fmaf(th2[5], RCP(EXP2(a1.y + b1.y) + 1.f), acc1);
        acc0 = fmaf(th2[6], RCP(EXP2(a1.z + b1.z) + 1.f), acc0);
        acc1 = fmaf(th2[7], RCP(EXP2(a1.w + b1.w) + 1.f), acc1);
        float acc = acc0 + acc1;
        // 16-lane butterfly in VALU (DPP) instead of dependent ds_swizzle
        acc = dpp_add<0xB1>(acc);
        acc = dpp_add<0x4E>(acc);
        acc = dpp_add<0x141>(acc);
        acc = dpp_add<0x140>(acc);       // identical across the 16 lanes
        float p = EXP2(acc) * wvt;       // exp(theta.tanh + gumbel), TAU=1
        if (p > pmax) { pmax = p; pidx = t; }   // strict > = first max
        psum += p;
        if (lk == 0) pout[vox + t * NVOX] = p;  // argmax slot fixed post-loop
        s0.x = fmaf(p, c0.x, s0.x); s0.y = fmaf(p, c0.y, s0.y);
        s0.z = fmaf(p, c0.z, s0.z); s0.w = fmaf(p, c0.w, s0.w);
        s1.x = fmaf(p, c1.x, s1.x); s1.y = fmaf(p, c1.y, s1.y);
        s1.z = fmaf(p, c1.z, s1.z); s1.w = fmaf(p, c1.w, s1.w);
        a0 = n0; a1 = n1; srcC = srcN;
    }
    // same-thread same-address store after the loop's store: program order holds
    if (lk == 0) pout[vox + pidx * NVOX] = -pmax;
    float* sr = sump + (size_t)vox * H;
    *(float4*)&sr[lk * 4]        = s0;
    *(float4*)&sr[(lk + 16) * 4] = s1;
    // psum identical within each 16-lane group -> xor 16/32 sums the 4 groups
    psum += __shfl_xor(psum, 16, 64);
    psum += __shfl_xor(psum, 32, 64);
    if (lane == 0) psums[wave] = psum;
    __syncthreads();                     // psums visible
    if (tid == 0)
        partial[blockIdx.x] = psums[0] + psums[1] + psums[2] + psums[3];
}

// ---- finalize: per-block redundant invS (3125 partials, L2-resident) + stream ----
// blocks [0,ABLK): vout = v + mask*invS*sump ; blocks [ABLK,2*ABLK): y, y_hard
__global__ __launch_bounds__(256) void k_out(const float* __restrict__ v,
                                             const float* __restrict__ maskp,
                                             const float* __restrict__ partial,
                                             float* __restrict__ vout,  // sump in
                                             float* __restrict__ ybuf,  // +-p in
                                             float* __restrict__ yhard) {
    __shared__ float wsum[4];
    int tid = threadIdx.x;
    float s = 0.f;
    for (int i = tid; i < NBLK; i += 256) s += partial[i];
#pragma unroll
    for (int off = 32; off >= 1; off >>= 1) s += __shfl_xor(s, off, 64);
    if ((tid & 63) == 0) wsum[tid >> 6] = s;
    __syncthreads();
    float invS = RCP(wsum[0] + wsum[1] + wsum[2] + wsum[3]);  // identical per block

    int bid = blockIdx.x;
    if (bid < ABLK) {
#pragma unroll
        for (int r = 0; r < 2; ++r) {
            int i = (bid + r * ABLK) * 256 + tid;
            float4 sp = ((const float4*)vout)[i];
            float4 vv = ((const float4*)v)[i];
            float  m  = maskp[i >> 5] * invS;
            float4 o;
            o.x = fmaf(m, sp.x, vv.x); o.y = fmaf(m, sp.y, vv.y);
            o.z = fmaf(m, sp.z, vv.z); o.w = fmaf(m, sp.w, vv.w);
            ((float4*)vout)[i] = o;
        }
    } else {
        int e = (bid - ABLK) * 256 + tid;
        float pv = ybuf[e];
        ybuf[e]  = fabsf(pv) * invS;
        yhard[e] = (pv < 0.f) ? 1.f : 0.f;
    }
}

extern "C" void kernel_launch(void* const* d_in, const int* in_sizes, int n_in,
                              void* d_out, int out_size, void* d_ws, size_t ws_size,
                              hipStream_t stream) {
    (void)in_sizes; (void)n_in; (void)out_size; (void)ws_size;
    const float* x   = (const float*)d_in[0];
    const float* v   = (const float*)d_in[1];
    const int*   cei = (const int*)d_in[2];
    const float* Wp  = (const float*)d_in[3];
    const float* bp  = (const float*)d_in[4];
    const float* Wv  = (const float*)d_in[5];
    const float* bv  = (const float*)d_in[6];
    const float* Wm1 = (const float*)d_in[7];
    const float* bm1 = (const float*)d_in[8];
    const float* Wm2 = (const float*)d_in[9];
    const float* bm2 = (const float*)d_in[10];
    const float* th  = (const float*)d_in[11];
    const float* gum = (const float*)d_in[12];

    float* out   = (float*)d_out;
    float* vout  = out;                          // [NV*H] sump until k_out
    float* maskp = out + (size_t)NVOX * H;       // [NV]
    float* ybuf  = maskp + NVOX;                 // [E]  +-p until k_out
    float* yhard = ybuf + NEDGE;                 // [E]  scratch until k_out
    float* xp    = yhard;                        // 65536 floats
    h16*   WvThi = (h16*)(yhard + 65536);        // 16384 h16
    h16*   WvTlo = WvThi + 16384;
    h16*   Wm1T  = WvThi + 32768;
    float* partial = (float*)d_ws;               // NBLK floats (~12.5 KB)

    k_pre<<<NP + 128, 256, 0, stream>>>(x, Wp, bp, Wv, Wm1, xp, WvThi, WvTlo, Wm1T);
    k_mainX<<<NBLK, 256, 0, stream>>>(v, x, bv, bm1, Wm2, bm2, WvThi, WvTlo, Wm1T,
                                      xp, cei, th, gum, maskp, ybuf, vout, partial);
    k_out<<<2 * ABLK, 256, 0, stream>>>(v, maskp, partial, vout, ybuf, yhard);
}

// Round 7
// 180.908 us; speedup vs baseline: 1.0832x; 1.0832x over previous
//
#include <hip/hip_runtime.h>

#define H     128
#define NP    512
#define NVOX  50000
#define NEDGE 800000
#define EPV   16
#define SLOPE 0.01f
#define GR    32                          // voxel rows per k_mainX block
#define NBLK  1563                        // ceil(NVOX/GR)
#define STRH  136                         // padded f16 LDS stride (halves)
#define VSTR  132                         // padded f32 LDS stride (floats)
#define C1    2.8853900817779268f         // 2*log2(e)
#define LOG2E 1.4426950408889634f
#define ABLK  3125                        // k_out part-A blocks

#define EXP2(x) __builtin_amdgcn_exp2f(x)
#define LOG2(x) __builtin_amdgcn_logf(x)
#define RCP(x)  __builtin_amdgcn_rcpf(x)

typedef _Float16 h16;
typedef __attribute__((ext_vector_type(4))) _Float16 h16x4;
typedef __attribute__((ext_vector_type(8))) _Float16 h16x8;
typedef __attribute__((ext_vector_type(4))) float    f32x4;

// DPP butterfly add: 0xB1=quad_perm[1,0,3,2] (xor1), 0x4E=quad_perm[2,3,0,1]
// (xor2), 0x141=row_half_mirror (xor4 once quads uniform), 0x140=row_mirror
// (xor8 once 8-groups uniform). Pure VALU, short dependency chain.
template <int CTRL>
__device__ __forceinline__ float dpp_add(float x) {
    union { float f; int i; } u, r;
    u.f = x;
    r.i = __builtin_amdgcn_update_dpp(0, u.i, CTRL, 0xf, 0xf, true);
    return x + r.f;
}

// ==== blocks [0,NP): xp' = (x@Wp+bp)*C1 ; [NP,NP+128): W split ;
//      [NP+128,NP+192): xh = f16(x)  (halves the edge loop's x-gather bytes) ====
__global__ __launch_bounds__(256) void k_pre(const float* __restrict__ x,
                                             const float* __restrict__ Wp,
                                             const float* __restrict__ bp,
                                             const float* __restrict__ Wv,
                                             const float* __restrict__ Wm1,
                                             float* __restrict__ xpout,
                                             h16* __restrict__ WvThi,
                                             h16* __restrict__ WvTlo,
                                             h16* __restrict__ Wm1T,
                                             h16* __restrict__ xh) {
    __shared__ float part[H];
    int bid = blockIdx.x;
    int tid = threadIdx.x;
    if (bid < NP) {
        int row = bid;
        int col = tid & 127;
        int kh  = tid >> 7;
        int kbase = kh * 64;
        const float* xr = x + (size_t)row * H;
        float acc = 0.f;
#pragma unroll 8
        for (int k = 0; k < 64; ++k)
            acc = fmaf(xr[kbase + k], Wp[(size_t)(kbase + k) * H + col], acc);
        if (kh == 1) part[col] = acc;
        __syncthreads();
        if (kh == 0) xpout[(size_t)row * H + col] = (acc + part[col] + bp[col]) * C1;
    } else if (bid < NP + 128) {
        int idx = (bid - NP) * 256 + tid;
        if (idx < 16384) {
            int k = idx >> 7, n = idx & 127;
            float w = Wv[idx];
            h16 hi = (h16)w;
            WvThi[n * H + k] = hi;
            WvTlo[n * H + k] = (h16)(w - (float)hi);
        } else {
            int j = idx - 16384;
            int k = j >> 7, n = j & 127;
            Wm1T[n * H + k] = (h16)Wm1[j];
        }
    } else {
        // f16 copy of x: 64 blocks x 256 threads x 4 elems = 65536
        int f4 = (bid - NP - 128) * 256 + tid;
        float4 val = *(const float4*)&x[(size_t)f4 * 4];
        h16x4 hv;
        hv.x = (h16)val.x; hv.y = (h16)val.y;
        hv.z = (h16)val.z; hv.w = (h16)val.w;
        *(h16x4*)&xh[(size_t)f4 * 4] = hv;
    }
}

// ======= fused: vv GEMM (LDS-only), mask, per-edge p (prefetched gathers),
//         sump = sum p*x[src] (x gathered in f16), per-block psum partial ====
// Theory: edge loop is L2-gather-BYTE-bound (819MB @ 11.6TB/s; occupancy,
// layout, VALU knobs all null). x->f16 cuts gather bytes 25%. xp stays f32:
// p feeds the per-voxel argmax (y_hard) -- f16 p-perturbation flips orderings.
__global__ __launch_bounds__(256, 4) void k_mainX(
    const float* __restrict__ v,   const h16* __restrict__ xh,
    const float* __restrict__ bv,  const float* __restrict__ bm1,
    const float* __restrict__ Wm2, const float* __restrict__ bm2,
    const h16* __restrict__ WvThi, const h16* __restrict__ WvTlo,
    const h16* __restrict__ Wm1T,
    const float* __restrict__ xp,  const int* __restrict__ cei,
    const float* __restrict__ theta, const float* __restrict__ gum,
    float* __restrict__ mask_out, float* __restrict__ pout,
    float* __restrict__ sump,     float* __restrict__ partial)
{
    __shared__ __align__(16) char ldsbuf[2 * GR * STRH * 2];  // 17408 B
    h16*   vh = (h16*)ldsbuf;            // [GR][STRH]
    h16*   vl = vh + GR * STRH;
    float* vt = (float*)ldsbuf;          // [GR][VSTR] f32 vv tile (reuse)
    __shared__ int   ceit[EPV * GR];     // [t*GR+c]
    __shared__ float gumt[EPV * GR];     // pre-transformed: exp(gumbel)
    __shared__ float pmbuf[4][GR];
    __shared__ float psums[4];

    int tid  = threadIdx.x;
    int base = blockIdx.x * GR;

    // ---- stage v tile (f16 hi/lo split) + cei/gum tiles (clamped tail) ----
#pragma unroll
    for (int i = 0; i < 4; ++i) {
        int f  = i * 256 + tid;          // 1024 float4 slots
        int r  = f >> 5, c4 = f & 31;
        int gr = base + r; if (gr >= NVOX) gr = NVOX - 1;
        float4 val = *(const float4*)&v[(size_t)gr * H + c4 * 4];
        h16x4 hi, lo;
        hi.x = (h16)val.x; lo.x = (h16)(val.x - (float)hi.x);
        hi.y = (h16)val.y; lo.y = (h16)(val.y - (float)hi.y);
        hi.z = (h16)val.z; lo.z = (h16)(val.z - (float)hi.z);
        hi.w = (h16)val.w; lo.w = (h16)(val.w - (float)hi.w);
        *(h16x4*)&vh[r * STRH + c4 * 4] = hi;
        *(h16x4*)&vl[r * STRH + c4 * 4] = lo;
    }
#pragma unroll
    for (int it = 0; it < 2; ++it) {
        int idx = it * 256 + tid;        // 512 slots
        int t = idx >> 5, c = idx & 31;
        int vx = base + c; if (vx >= NVOX) vx = NVOX - 1;
        int e = vx + t * NVOX;
        ceit[idx] = cei[e];
        gumt[idx] = -LOG2E * RCP(LOG2(gum[e]));   // exp(gumbel) hoisted
    }
    __syncthreads();

    // ---- dual GEMM via MFMA 16x16x32 f16 (split hi/lo for Wv) ----
    int wave = tid >> 6, lane = tid & 63;
    int m16 = lane & 15, quad = lane >> 4;
    int cb = wave * 32;

    f32x4 aV[2][2], aM[2][2];
#pragma unroll
    for (int rt = 0; rt < 2; ++rt)
#pragma unroll
        for (int ct = 0; ct < 2; ++ct) { aV[rt][ct] = (f32x4)0.f; aM[rt][ct] = (f32x4)0.f; }

#pragma unroll
    for (int kc = 0; kc < 4; ++kc) {
        int kofs = kc * 32 + quad * 8;
        h16x8 ah[2], al[2];
#pragma unroll
        for (int rt = 0; rt < 2; ++rt) {
            int row = rt * 16 + m16;
            ah[rt] = *(const h16x8*)&vh[row * STRH + kofs];
            al[rt] = *(const h16x8*)&vl[row * STRH + kofs];
        }
#pragma unroll
        for (int ct = 0; ct < 2; ++ct) {
            int n = cb + ct * 16 + m16;
            h16x8 bh = *(const h16x8*)&WvThi[n * H + kofs];
            h16x8 bl = *(const h16x8*)&WvTlo[n * H + kofs];
            h16x8 bm = *(const h16x8*)&Wm1T[n * H + kofs];
#pragma unroll
            for (int rt = 0; rt < 2; ++rt) {
                aV[rt][ct] = __builtin_amdgcn_mfma_f32_16x16x32_f16(ah[rt], bh, aV[rt][ct], 0, 0, 0);
                aV[rt][ct] = __builtin_amdgcn_mfma_f32_16x16x32_f16(al[rt], bh, aV[rt][ct], 0, 0, 0);
                aV[rt][ct] = __builtin_amdgcn_mfma_f32_16x16x32_f16(ah[rt], bl, aV[rt][ct], 0, 0, 0);
                aM[rt][ct] = __builtin_amdgcn_mfma_f32_16x16x32_f16(ah[rt], bm, aM[rt][ct], 0, 0, 0);
            }
        }
    }
    __syncthreads();                     // vh/vl fully consumed

    // ---- write vv tile (prescaled by C1) to LDS + mask partials ----
    float pml[2][4];
#pragma unroll
    for (int rt = 0; rt < 2; ++rt)
#pragma unroll
        for (int reg = 0; reg < 4; ++reg) pml[rt][reg] = 0.f;
#pragma unroll
    for (int ct = 0; ct < 2; ++ct) {
        int col = cb + ct * 16 + m16;
        float bvc = bv[col], bmc = bm1[col], w2c = Wm2[col];
#pragma unroll
        for (int rt = 0; rt < 2; ++rt)
#pragma unroll
            for (int reg = 0; reg < 4; ++reg) {
                int row = rt * 16 + quad * 4 + reg;
                vt[row * VSTR + col] = (aV[rt][ct][reg] + bvc) * C1;
                float m = aM[rt][ct][reg] + bmc;
                m = (m >= 0.f) ? m : SLOPE * m;
                pml[rt][reg] = fmaf(m, w2c, pml[rt][reg]);
            }
    }
#pragma unroll
    for (int rt = 0; rt < 2; ++rt)
#pragma unroll
        for (int reg = 0; reg < 4; ++reg) {  // sum over m16 (16 lanes), VALU DPP
            pml[rt][reg] = dpp_add<0xB1>(pml[rt][reg]);
            pml[rt][reg] = dpp_add<0x4E>(pml[rt][reg]);
            pml[rt][reg] = dpp_add<0x141>(pml[rt][reg]);
            pml[rt][reg] = dpp_add<0x140>(pml[rt][reg]);
        }
    if (m16 == 0) {
#pragma unroll
        for (int rt = 0; rt < 2; ++rt)
#pragma unroll
            for (int reg = 0; reg < 4; ++reg)
                pmbuf[wave][rt * 16 + quad * 4 + reg] = pml[rt][reg];
    }
    __syncthreads();                     // vt + pmbuf visible
    if (wave == 0 && lane < GR) {
        int gr = base + lane;
        if (gr < NVOX) {
            float s = pmbuf[0][lane] + pmbuf[1][lane] + pmbuf[2][lane]
                    + pmbuf[3][lane] + bm2[0];
            mask_out[gr] = RCP(1.f + EXP2(-s * LOG2E));
        }
    }

    // ---- edges: 8 lanes/edge, group g owns voxel base+g ----
    int g = tid >> 3, lk = tid & 7;
    int vox = base + g;
    bool valid = vox < NVOX;
    float th2[16], thsum = 0.f;
#pragma unroll
    for (int i = 0; i < 4; ++i) {
        float4 t4 = *(const float4*)&theta[(lk + 8 * i) * 4];
        th2[i * 4 + 0] = -2.f * LOG2E * t4.x; th2[i * 4 + 1] = -2.f * LOG2E * t4.y;
        th2[i * 4 + 2] = -2.f * LOG2E * t4.z; th2[i * 4 + 3] = -2.f * LOG2E * t4.w;
        thsum += LOG2E * (t4.x + t4.y + t4.z + t4.w);
    }
    const float* vr = &vt[g * VSTR];
    float4 b0 = *(const float4*)&vr[(lk +  0) * 4];
    float4 b1 = *(const float4*)&vr[(lk +  8) * 4];
    float4 b2 = *(const float4*)&vr[(lk + 16) * 4];
    float4 b3 = *(const float4*)&vr[(lk + 24) * 4];

    float4 s0 = make_float4(0.f,0.f,0.f,0.f), s1 = s0, s2 = s0, s3 = s0;
    float psum = 0.f, pmax = -1.f;
    int   pidx = 0;

    int srcC = ceit[g];                  // t = 0
    const float4* xr0 = (const float4*)(xp + (size_t)srcC * H);
    float4 a0 = xr0[lk], a1 = xr0[lk + 8], a2 = xr0[lk + 16], a3 = xr0[lk + 24];

    for (int t = 0; t < EPV; ++t) {
        // prefetch next xp row (the latency-exposed gather)
        float4 n0, n1, n2, n3;
        int srcN;
        if (t < EPV - 1) {
            srcN = ceit[(t + 1) * GR + g];
            const float4* xrN = (const float4*)(xp + (size_t)srcN * H);
            n0 = xrN[lk]; n1 = xrN[lk + 8]; n2 = xrN[lk + 16]; n3 = xrN[lk + 24];
        } else {
            srcN = srcC; n0 = a0; n1 = a1; n2 = a2; n3 = a3;
        }
        // x row in f16 (half the bytes); fmaf(p,(float)h,s) -> v_fma_mix_f32
        const h16* xo = xh + (size_t)srcC * H;
        h16x4 c0 = *(const h16x4*)&xo[(lk +  0) * 4];
        h16x4 c1 = *(const h16x4*)&xo[(lk +  8) * 4];
        h16x4 c2 = *(const h16x4*)&xo[(lk + 16) * 4];
        h16x4 c3 = *(const h16x4*)&xo[(lk + 24) * 4];
        float wvt = gumt[t * GR + g];    // exp(gumbel), pre-transformed

        float acc0 = thsum, acc1 = 0.f;
        acc0 = fmaf(th2[ 0], RCP(EXP2(a0.x + b0.x) + 1.f), acc0);
        acc1 = fmaf(th2[ 1], RCP(EXP2(a0.y + b0.y) + 1.f), acc1);
        acc0 = fmaf(th2[ 2], RCP(EXP2(a0.z + b0.z) + 1.f), acc0);
        acc1 = fmaf(th2[ 3], RCP(EXP2(a0.w + b0.w) + 1.f), acc1);
        acc0 = fmaf(th2[ 4], RCP(EXP2(a1.x + b1.x) + 1.f), acc0);
        acc1 = fmaf(th2[ 5], RCP(EXP2(a1.y + b1.y) + 1.f), acc1);
        acc0 = fmaf(th2[ 6], RCP(EXP2(a1.z + b1.z) + 1.f), acc0);
        acc1 = fmaf(th2[ 7], RCP(EXP2(a1.w + b1.w) + 1.f), acc1);
        acc0 = fmaf(th2[ 8], RCP(EXP2(a2.x + b2.x) + 1.f), acc0);
        acc1 = fmaf(th2[ 9], RCP(EXP2(a2.y + b2.y) + 1.f), acc1);
        acc0 = fmaf(th2[10], RCP(EXP2(a2.z + b2.z) + 1.f), acc0);
        acc1 = fmaf(th2[11], RCP(EXP2(a2.w + b2.w) + 1.f), acc1);
        acc0 = fmaf(th2[12], RCP(EXP2(a3.x + b3.x) + 1.f), acc0);
        acc1 = fmaf(th2[13], RCP(EXP2(a3.y + b3.y) + 1.f), acc1);
        acc0 = fmaf(th2[14], RCP(EXP2(a3.z + b3.z) + 1.f), acc0);
        acc1 = fmaf(th2[15], RCP(EXP2(a3.w + b3.w) + 1.f), acc1);
        float acc = acc0 + acc1;
        // 8-lane butterfly in VALU (DPP) instead of dependent ds_swizzle
        acc = dpp_add<0xB1>(acc);
        acc = dpp_add<0x4E>(acc);
        acc = dpp_add<0x141>(acc);       // identical across the 8 lanes
        float p = EXP2(acc) * wvt;       // exp(theta.tanh + gumbel), TAU=1
        if (p > pmax) { pmax = p; pidx = t; }   // strict > = first max
        if (valid) psum += p;
        if (lk == 0 && valid) pout[vox + t * NVOX] = p;  // argmax fixed post-loop
        s0.x = fmaf(p, (float)c0.x, s0.x); s0.y = fmaf(p, (float)c0.y, s0.y);
        s0.z = fmaf(p, (float)c0.z, s0.z); s0.w = fmaf(p, (float)c0.w, s0.w);
        s1.x = fmaf(p, (float)c1.x, s1.x); s1.y = fmaf(p, (float)c1.y, s1.y);
        s1.z = fmaf(p, (float)c1.z, s1.z); s1.w = fmaf(p, (float)c1.w, s1.w);
        s2.x = fmaf(p, (float)c2.x, s2.x); s2.y = fmaf(p, (float)c2.y, s2.y);
        s2.z = fmaf(p, (float)c2.z, s2.z); s2.w = fmaf(p, (float)c2.w, s2.w);
        s3.x = fmaf(p, (float)c3.x, s3.x); s3.y = fmaf(p, (float)c3.y, s3.y);
        s3.z = fmaf(p, (float)c3.z, s3.z); s3.w = fmaf(p, (float)c3.w, s3.w);
        a0 = n0; a1 = n1; a2 = n2; a3 = n3; srcC = srcN;
    }
    // same-thread same-address store after the loop's store: program order holds
    if (lk == 0 && valid) pout[vox + pidx * NVOX] = -pmax;
    if (valid) {
        float* sr = sump + (size_t)vox * H;
        *(float4*)&sr[(lk +  0) * 4] = s0;
        *(float4*)&sr[(lk +  8) * 4] = s1;
        *(float4*)&sr[(lk + 16) * 4] = s2;
        *(float4*)&sr[(lk + 24) * 4] = s3;
    }
    // wave psum: groups occupy disjoint 8-lane slots -> xor 8/16/32 sums each once
    psum += __shfl_xor(psum, 8, 64);
    psum += __shfl_xor(psum, 16, 64);
    psum += __shfl_xor(psum, 32, 64);
    if (lane == 0) psums[wave] = psum;
    __syncthreads();                     // psums visible
    if (tid == 0)
        partial[blockIdx.x] = psums[0] + psums[1] + psums[2] + psums[3];
}

// ---- finalize: per-block redundant invS (1563 partials, L2-resident) + stream ----
// blocks [0,ABLK): vout = v + mask*invS*sump ; blocks [ABLK,2*ABLK): y, y_hard
__global__ __launch_bounds__(256) void k_out(const float* __restrict__ v,
                                             const float* __restrict__ maskp,
                                             const float* __restrict__ partial,
                                             float* __restrict__ vout,  // sump in
                                             float* __restrict__ ybuf,  // +-p in
                                             float* __restrict__ yhard) {
    __shared__ float wsum[4];
    int tid = threadIdx.x;
    float s = 0.f;
    for (int i = tid; i < NBLK; i += 256) s += partial[i];
#pragma unroll
    for (int off = 32; off >= 1; off >>= 1) s += __shfl_xor(s, off, 64);
    if ((tid & 63) == 0) wsum[tid >> 6] = s;
    __syncthreads();
    float invS = RCP(wsum[0] + wsum[1] + wsum[2] + wsum[3]);  // identical per block

    int bid = blockIdx.x;
    if (bid < ABLK) {
#pragma unroll
        for (int r = 0; r < 2; ++r) {
            int i = (bid + r * ABLK) * 256 + tid;
            float4 sp = ((const float4*)vout)[i];
            float4 vv = ((const float4*)v)[i];
            float  m  = maskp[i >> 5] * invS;
            float4 o;
            o.x = fmaf(m, sp.x, vv.x); o.y = fmaf(m, sp.y, vv.y);
            o.z = fmaf(m, sp.z, vv.z); o.w = fmaf(m, sp.w, vv.w);
            ((float4*)vout)[i] = o;
        }
    } else {
        int e = (bid - ABLK) * 256 + tid;
        float pv = ybuf[e];
        ybuf[e]  = fabsf(pv) * invS;
        yhard[e] = (pv < 0.f) ? 1.f : 0.f;
    }
}

extern "C" void kernel_launch(void* const* d_in, const int* in_sizes, int n_in,
                              void* d_out, int out_size, void* d_ws, size_t ws_size,
                              hipStream_t stream) {
    (void)in_sizes; (void)n_in; (void)out_size; (void)ws_size;
    const float* x   = (const float*)d_in[0];
    const float* v   = (const float*)d_in[1];
    const int*   cei = (const int*)d_in[2];
    const float* Wp  = (const float*)d_in[3];
    const float* bp  = (const float*)d_in[4];
    const float* Wv  = (const float*)d_in[5];
    const float* bv  = (const float*)d_in[6];
    const float* Wm1 = (const float*)d_in[7];
    const float* bm1 = (const float*)d_in[8];
    const float* Wm2 = (const float*)d_in[9];
    const float* bm2 = (const float*)d_in[10];
    const float* th  = (const float*)d_in[11];
    const float* gum = (const float*)d_in[12];

    float* out   = (float*)d_out;
    float* vout  = out;                          // [NV*H] sump until k_out
    float* maskp = out + (size_t)NVOX * H;       // [NV]
    float* ybuf  = maskp + NVOX;                 // [E]  +-p until k_out
    float* yhard = ybuf + NEDGE;                 // [E]  scratch until k_out
    float* xp    = yhard;                        // 65536 floats (256 KB)
    h16*   WvThi = (h16*)(yhard + 65536);        // 16384 h16
    h16*   WvTlo = WvThi + 16384;
    h16*   Wm1T  = WvThi + 32768;
    h16*   xh    = WvThi + 49152;                // 65536 h16 (128 KB)
    float* partial = (float*)d_ws;               // NBLK floats (~6.3 KB)

    k_pre<<<NP + 192, 256, 0, stream>>>(x, Wp, bp, Wv, Wm1, xp, WvThi, WvTlo,
                                        Wm1T, xh);
    k_mainX<<<NBLK, 256, 0, stream>>>(v, xh, bv, bm1, Wm2, bm2, WvThi, WvTlo,
                                      Wm1T, xp, cei, th, gum, maskp, ybuf, vout,
                                      partial);
    k_out<<<2 * ABLK, 256, 0, stream>>>(v, maskp, partial, vout, ybuf, yhard);
}

// Round 8
// 178.750 us; speedup vs baseline: 1.0963x; 1.0121x over previous
//
#include <hip/hip_runtime.h>

#define H     128
#define NP    512
#define NVOX  50000
#define NEDGE 800000
#define EPV   16
#define SLOPE 0.01f
#define GR    32                          // voxel rows per k_mainX block
#define NBLK  1563                        // ceil(NVOX/GR)
#define STRH  136                         // padded f16 LDS stride (halves)
#define VSTR  132                         // padded f32 LDS stride (floats)
#define C1    2.8853900817779268f         // 2*log2(e)
#define LOG2E 1.4426950408889634f
#define ABLK  3125                        // k_out part-A blocks

#define EXP2(x) __builtin_amdgcn_exp2f(x)
#define LOG2(x) __builtin_amdgcn_logf(x)
#define RCP(x)  __builtin_amdgcn_rcpf(x)

typedef _Float16 h16;
typedef __attribute__((ext_vector_type(4))) _Float16 h16x4;
typedef __attribute__((ext_vector_type(8))) _Float16 h16x8;
typedef __attribute__((ext_vector_type(4))) float    f32x4;

// DPP butterfly add: 0xB1=quad_perm[1,0,3,2] (xor1), 0x4E=quad_perm[2,3,0,1]
// (xor2), 0x141=row_half_mirror (xor4 once quads uniform). Pure VALU.
template <int CTRL>
__device__ __forceinline__ float dpp_add(float x) {
    union { float f; int i; } u, r;
    u.f = x;
    r.i = __builtin_amdgcn_update_dpp(0, u.i, CTRL, 0xf, 0xf, true);
    return x + r.f;
}

// ==== blocks [0,NP): xp' = (x@Wp+bp)*C1 ; [NP,NP+128): W split ;
//      [NP+128,NP+192): xh = f16(x) ====
__global__ __launch_bounds__(256) void k_pre(const float* __restrict__ x,
                                             const float* __restrict__ Wp,
                                             const float* __restrict__ bp,
                                             const float* __restrict__ Wv,
                                             const float* __restrict__ Wm1,
                                             float* __restrict__ xpout,
                                             h16* __restrict__ WvThi,
                                             h16* __restrict__ WvTlo,
                                             h16* __restrict__ Wm1T,
                                             h16* __restrict__ xh) {
    __shared__ float part[H];
    int bid = blockIdx.x;
    int tid = threadIdx.x;
    if (bid < NP) {
        int row = bid;
        int col = tid & 127;
        int kh  = tid >> 7;
        int kbase = kh * 64;
        const float* xr = x + (size_t)row * H;
        float acc = 0.f;
#pragma unroll 8
        for (int k = 0; k < 64; ++k)
            acc = fmaf(xr[kbase + k], Wp[(size_t)(kbase + k) * H + col], acc);
        if (kh == 1) part[col] = acc;
        __syncthreads();
        if (kh == 0) xpout[(size_t)row * H + col] = (acc + part[col] + bp[col]) * C1;
    } else if (bid < NP + 128) {
        int idx = (bid - NP) * 256 + tid;
        if (idx < 16384) {
            int k = idx >> 7, n = idx & 127;
            float w = Wv[idx];
            h16 hi = (h16)w;
            WvThi[n * H + k] = hi;
            WvTlo[n * H + k] = (h16)(w - (float)hi);
        } else {
            int j = idx - 16384;
            int k = j >> 7, n = j & 127;
            Wm1T[n * H + k] = (h16)Wm1[j];
        }
    } else {
        // f16 copy of x: 64 blocks x 256 threads x 4 elems = 65536
        int f4 = (bid - NP - 128) * 256 + tid;
        float4 val = *(const float4*)&x[(size_t)f4 * 4];
        h16x4 hv;
        hv.x = (h16)val.x; hv.y = (h16)val.y;
        hv.z = (h16)val.z; hv.w = (h16)val.w;
        *(h16x4*)&xh[(size_t)f4 * 4] = hv;
    }
}

// ======= fused: vv GEMM (LDS-only), mask, per-edge p, sump, psum partial ====
// ROUND 8 FIX: the old loop loaded x(t) AFTER the xp(t+1) prefetch and used
// it LAST -> the s-accum's s_waitcnt was vmcnt(0), draining the prefetch
// every iteration (vmcnt is FIFO). Now BOTH xp(t+1) and x(t+1) are issued at
// the top of iteration t and consumed one iteration later, in issue order:
// all waits become vmcnt(8)-class, the pipe never drains, every gather gets
// a full iteration to land. (T4 counted-vmcnt pattern, plain-HIP form.)
__global__ __launch_bounds__(256, 4) void k_mainX(
    const float* __restrict__ v,   const h16* __restrict__ xh,
    const float* __restrict__ bv,  const float* __restrict__ bm1,
    const float* __restrict__ Wm2, const float* __restrict__ bm2,
    const h16* __restrict__ WvThi, const h16* __restrict__ WvTlo,
    const h16* __restrict__ Wm1T,
    const float* __restrict__ xp,  const int* __restrict__ cei,
    const float* __restrict__ theta, const float* __restrict__ gum,
    float* __restrict__ mask_out, float* __restrict__ pout,
    float* __restrict__ sump,     float* __restrict__ partial)
{
    __shared__ __align__(16) char ldsbuf[2 * GR * STRH * 2];  // 17408 B
    h16*   vh = (h16*)ldsbuf;            // [GR][STRH]
    h16*   vl = vh + GR * STRH;
    float* vt = (float*)ldsbuf;          // [GR][VSTR] f32 vv tile (reuse)
    __shared__ int   ceit[EPV * GR];     // [t*GR+c]
    __shared__ float gumt[EPV * GR];     // pre-transformed: exp(gumbel)
    __shared__ float pmbuf[4][GR];
    __shared__ float psums[4];

    int tid  = threadIdx.x;
    int base = blockIdx.x * GR;

    // ---- stage v tile (f16 hi/lo split) + cei/gum tiles (clamped tail) ----
#pragma unroll
    for (int i = 0; i < 4; ++i) {
        int f  = i * 256 + tid;          // 1024 float4 slots
        int r  = f >> 5, c4 = f & 31;
        int gr = base + r; if (gr >= NVOX) gr = NVOX - 1;
        float4 val = *(const float4*)&v[(size_t)gr * H + c4 * 4];
        h16x4 hi, lo;
        hi.x = (h16)val.x; lo.x = (h16)(val.x - (float)hi.x);
        hi.y = (h16)val.y; lo.y = (h16)(val.y - (float)hi.y);
        hi.z = (h16)val.z; lo.z = (h16)(val.z - (float)hi.z);
        hi.w = (h16)val.w; lo.w = (h16)(val.w - (float)hi.w);
        *(h16x4*)&vh[r * STRH + c4 * 4] = hi;
        *(h16x4*)&vl[r * STRH + c4 * 4] = lo;
    }
#pragma unroll
    for (int it = 0; it < 2; ++it) {
        int idx = it * 256 + tid;        // 512 slots
        int t = idx >> 5, c = idx & 31;
        int vx = base + c; if (vx >= NVOX) vx = NVOX - 1;
        int e = vx + t * NVOX;
        ceit[idx] = cei[e];
        gumt[idx] = -LOG2E * RCP(LOG2(gum[e]));   // exp(gumbel) hoisted
    }
    __syncthreads();

    // ---- dual GEMM via MFMA 16x16x32 f16 (split hi/lo for Wv) ----
    int wave = tid >> 6, lane = tid & 63;
    int m16 = lane & 15, quad = lane >> 4;
    int cb = wave * 32;

    f32x4 aV[2][2], aM[2][2];
#pragma unroll
    for (int rt = 0; rt < 2; ++rt)
#pragma unroll
        for (int ct = 0; ct < 2; ++ct) { aV[rt][ct] = (f32x4)0.f; aM[rt][ct] = (f32x4)0.f; }

#pragma unroll
    for (int kc = 0; kc < 4; ++kc) {
        int kofs = kc * 32 + quad * 8;
        h16x8 ah[2], al[2];
#pragma unroll
        for (int rt = 0; rt < 2; ++rt) {
            int row = rt * 16 + m16;
            ah[rt] = *(const h16x8*)&vh[row * STRH + kofs];
            al[rt] = *(const h16x8*)&vl[row * STRH + kofs];
        }
#pragma unroll
        for (int ct = 0; ct < 2; ++ct) {
            int n = cb + ct * 16 + m16;
            h16x8 bh = *(const h16x8*)&WvThi[n * H + kofs];
            h16x8 bl = *(const h16x8*)&WvTlo[n * H + kofs];
            h16x8 bm = *(const h16x8*)&Wm1T[n * H + kofs];
#pragma unroll
            for (int rt = 0; rt < 2; ++rt) {
                aV[rt][ct] = __builtin_amdgcn_mfma_f32_16x16x32_f16(ah[rt], bh, aV[rt][ct], 0, 0, 0);
                aV[rt][ct] = __builtin_amdgcn_mfma_f32_16x16x32_f16(al[rt], bh, aV[rt][ct], 0, 0, 0);
                aV[rt][ct] = __builtin_amdgcn_mfma_f32_16x16x32_f16(ah[rt], bl, aV[rt][ct], 0, 0, 0);
                aM[rt][ct] = __builtin_amdgcn_mfma_f32_16x16x32_f16(ah[rt], bm, aM[rt][ct], 0, 0, 0);
            }
        }
    }
    __syncthreads();                     // vh/vl fully consumed

    // ---- write vv tile (prescaled by C1) to LDS + mask partials ----
    float pml[2][4];
#pragma unroll
    for (int rt = 0; rt < 2; ++rt)
#pragma unroll
        for (int reg = 0; reg < 4; ++reg) pml[rt][reg] = 0.f;
#pragma unroll
    for (int ct = 0; ct < 2; ++ct) {
        int col = cb + ct * 16 + m16;
        float bvc = bv[col], bmc = bm1[col], w2c = Wm2[col];
#pragma unroll
        for (int rt = 0; rt < 2; ++rt)
#pragma unroll
            for (int reg = 0; reg < 4; ++reg) {
                int row = rt * 16 + quad * 4 + reg;
                vt[row * VSTR + col] = (aV[rt][ct][reg] + bvc) * C1;
                float m = aM[rt][ct][reg] + bmc;
                m = (m >= 0.f) ? m : SLOPE * m;
                pml[rt][reg] = fmaf(m, w2c, pml[rt][reg]);
            }
    }
#pragma unroll
    for (int rt = 0; rt < 2; ++rt)
#pragma unroll
        for (int reg = 0; reg < 4; ++reg) {  // sum over m16 (16 lanes), VALU DPP
            pml[rt][reg] = dpp_add<0xB1>(pml[rt][reg]);
            pml[rt][reg] = dpp_add<0x4E>(pml[rt][reg]);
            pml[rt][reg] = dpp_add<0x141>(pml[rt][reg]);
            pml[rt][reg] = dpp_add<0x140>(pml[rt][reg]);
        }
    if (m16 == 0) {
#pragma unroll
        for (int rt = 0; rt < 2; ++rt)
#pragma unroll
            for (int reg = 0; reg < 4; ++reg)
                pmbuf[wave][rt * 16 + quad * 4 + reg] = pml[rt][reg];
    }
    __syncthreads();                     // vt + pmbuf visible
    if (wave == 0 && lane < GR) {
        int gr = base + lane;
        if (gr < NVOX) {
            float s = pmbuf[0][lane] + pmbuf[1][lane] + pmbuf[2][lane]
                    + pmbuf[3][lane] + bm2[0];
            mask_out[gr] = RCP(1.f + EXP2(-s * LOG2E));
        }
    }

    // ---- edges: 8 lanes/edge, group g owns voxel base+g ----
    int g = tid >> 3, lk = tid & 7;
    int vox = base + g;
    bool valid = vox < NVOX;
    float th2[16], thsum = 0.f;
#pragma unroll
    for (int i = 0; i < 4; ++i) {
        float4 t4 = *(const float4*)&theta[(lk + 8 * i) * 4];
        th2[i * 4 + 0] = -2.f * LOG2E * t4.x; th2[i * 4 + 1] = -2.f * LOG2E * t4.y;
        th2[i * 4 + 2] = -2.f * LOG2E * t4.z; th2[i * 4 + 3] = -2.f * LOG2E * t4.w;
        thsum += LOG2E * (t4.x + t4.y + t4.z + t4.w);
    }
    const float* vr = &vt[g * VSTR];
    float4 b0 = *(const float4*)&vr[(lk +  0) * 4];
    float4 b1 = *(const float4*)&vr[(lk +  8) * 4];
    float4 b2 = *(const float4*)&vr[(lk + 16) * 4];
    float4 b3 = *(const float4*)&vr[(lk + 24) * 4];

    float4 s0 = make_float4(0.f,0.f,0.f,0.f), s1 = s0, s2 = s0, s3 = s0;
    float psum = 0.f, pmax = -1.f;
    int   pidx = 0;

    // prologue: load BOTH xp and x rows for t=0 (generation "current")
    int src0 = ceit[g];
    const float4* r0 = (const float4*)(xp + (size_t)src0 * H);
    float4 a0 = r0[lk], a1 = r0[lk + 8], a2 = r0[lk + 16], a3 = r0[lk + 24];
    const h16x4* q0 = (const h16x4*)(xh + (size_t)src0 * H);
    h16x4 c0 = q0[lk], c1 = q0[lk + 8], c2 = q0[lk + 16], c3 = q0[lk + 24];

    for (int t = 0; t < EPV; ++t) {
        // issue NEXT generation first: xp(t+1) then x(t+1). Everything this
        // iteration consumes (a*, c*) is OLDER than these 8 loads -> the
        // compiler's waits are vmcnt(8)-class, never a drain.
        float4 n0, n1, n2, n3;
        h16x4 d0, d1, d2, d3;
        int srcN;
        if (t < EPV - 1) {
            srcN = ceit[(t + 1) * GR + g];
            const float4* rN = (const float4*)(xp + (size_t)srcN * H);
            n0 = rN[lk]; n1 = rN[lk + 8]; n2 = rN[lk + 16]; n3 = rN[lk + 24];
            const h16x4* qN = (const h16x4*)(xh + (size_t)srcN * H);
            d0 = qN[lk]; d1 = qN[lk + 8]; d2 = qN[lk + 16]; d3 = qN[lk + 24];
        } else {
            srcN = src0; n0 = a0; n1 = a1; n2 = a2; n3 = a3;
            d0 = c0; d1 = c1; d2 = c2; d3 = c3;
        }
        float wvt = gumt[t * GR + g];    // exp(gumbel), pre-transformed

        float acc0 = thsum, acc1 = 0.f;
        acc0 = fmaf(th2[ 0], RCP(EXP2(a0.x + b0.x) + 1.f), acc0);
        acc1 = fmaf(th2[ 1], RCP(EXP2(a0.y + b0.y) + 1.f), acc1);
        acc0 = fmaf(th2[ 2], RCP(EXP2(a0.z + b0.z) + 1.f), acc0);
        acc1 = fmaf(th2[ 3], RCP(EXP2(a0.w + b0.w) + 1.f), acc1);
        acc0 = fmaf(th2[ 4], RCP(EXP2(a1.x + b1.x) + 1.f), acc0);
        acc1 = fmaf(th2[ 5], RCP(EXP2(a1.y + b1.y) + 1.f), acc1);
        acc0 = fmaf(th2[ 6], RCP(EXP2(a1.z + b1.z) + 1.f), acc0);
        acc1 = fmaf(th2[ 7], RCP(EXP2(a1.w + b1.w) + 1.f), acc1);
        acc0 = fmaf(th2[ 8], RCP(EXP2(a2.x + b2.x) + 1.f), acc0);
        acc1 = fmaf(th2[ 9], RCP(EXP2(a2.y + b2.y) + 1.f), acc1);
        acc0 = fmaf(th2[10], RCP(EXP2(a2.z + b2.z) + 1.f), acc0);
        acc1 = fmaf(th2[11], RCP(EXP2(a2.w + b2.w) + 1.f), acc1);
        acc0 = fmaf(th2[12], RCP(EXP2(a3.x + b3.x) + 1.f), acc0);
        acc1 = fmaf(th2[13], RCP(EXP2(a3.y + b3.y) + 1.f), acc1);
        acc0 = fmaf(th2[14], RCP(EXP2(a3.z + b3.z) + 1.f), acc0);
        acc1 = fmaf(th2[15], RCP(EXP2(a3.w + b3.w) + 1.f), acc1);
        float acc = acc0 + acc1;
        // 8-lane butterfly in VALU (DPP)
        acc = dpp_add<0xB1>(acc);
        acc = dpp_add<0x4E>(acc);
        acc = dpp_add<0x141>(acc);       // identical across the 8 lanes
        float p = EXP2(acc) * wvt;       // exp(theta.tanh + gumbel), TAU=1
        if (p > pmax) { pmax = p; pidx = t; }   // strict > = first max
        if (valid) psum += p;
        if (lk == 0 && valid) pout[vox + t * NVOX] = p;  // argmax fixed post-loop
        // s-accum uses c* = x(t), loaded one iteration ago (vmcnt(8), no drain)
        s0.x = fmaf(p, (float)c0.x, s0.x); s0.y = fmaf(p, (float)c0.y, s0.y);
        s0.z = fmaf(p, (float)c0.z, s0.z); s0.w = fmaf(p, (float)c0.w, s0.w);
        s1.x = fmaf(p, (float)c1.x, s1.x); s1.y = fmaf(p, (float)c1.y, s1.y);
        s1.z = fmaf(p, (float)c1.z, s1.z); s1.w = fmaf(p, (float)c1.w, s1.w);
        s2.x = fmaf(p, (float)c2.x, s2.x); s2.y = fmaf(p, (float)c2.y, s2.y);
        s2.z = fmaf(p, (float)c2.z, s2.z); s2.w = fmaf(p, (float)c2.w, s2.w);
        s3.x = fmaf(p, (float)c3.x, s3.x); s3.y = fmaf(p, (float)c3.y, s3.y);
        s3.z = fmaf(p, (float)c3.z, s3.z); s3.w = fmaf(p, (float)c3.w, s3.w);
        a0 = n0; a1 = n1; a2 = n2; a3 = n3;
        c0 = d0; c1 = d1; c2 = d2; c3 = d3;
        src0 = srcN;
    }
    // same-thread same-address store after the loop's store: program order holds
    if (lk == 0 && valid) pout[vox + pidx * NVOX] = -pmax;
    if (valid) {
        float* sr = sump + (size_t)vox * H;
        *(float4*)&sr[(lk +  0) * 4] = s0;
        *(float4*)&sr[(lk +  8) * 4] = s1;
        *(float4*)&sr[(lk + 16) * 4] = s2;
        *(float4*)&sr[(lk + 24) * 4] = s3;
    }
    // wave psum: groups occupy disjoint 8-lane slots -> xor 8/16/32 sums each once
    psum += __shfl_xor(psum, 8, 64);
    psum += __shfl_xor(psum, 16, 64);
    psum += __shfl_xor(psum, 32, 64);
    if (lane == 0) psums[wave] = psum;
    __syncthreads();                     // psums visible
    if (tid == 0)
        partial[blockIdx.x] = psums[0] + psums[1] + psums[2] + psums[3];
}

// ---- finalize: per-block redundant invS (1563 partials, L2-resident) + stream ----
// blocks [0,ABLK): vout = v + mask*invS*sump ; blocks [ABLK,2*ABLK): y, y_hard
__global__ __launch_bounds__(256) void k_out(const float* __restrict__ v,
                                             const float* __restrict__ maskp,
                                             const float* __restrict__ partial,
                                             float* __restrict__ vout,  // sump in
                                             float* __restrict__ ybuf,  // +-p in
                                             float* __restrict__ yhard) {
    __shared__ float wsum[4];
    int tid = threadIdx.x;
    float s = 0.f;
    for (int i = tid; i < NBLK; i += 256) s += partial[i];
#pragma unroll
    for (int off = 32; off >= 1; off >>= 1) s += __shfl_xor(s, off, 64);
    if ((tid & 63) == 0) wsum[tid >> 6] = s;
    __syncthreads();
    float invS = RCP(wsum[0] + wsum[1] + wsum[2] + wsum[3]);  // identical per block

    int bid = blockIdx.x;
    if (bid < ABLK) {
#pragma unroll
        for (int r = 0; r < 2; ++r) {
            int i = (bid + r * ABLK) * 256 + tid;
            float4 sp = ((const float4*)vout)[i];
            float4 vv = ((const float4*)v)[i];
            float  m  = maskp[i >> 5] * invS;
            float4 o;
            o.x = fmaf(m, sp.x, vv.x); o.y = fmaf(m, sp.y, vv.y);
            o.z = fmaf(m, sp.z, vv.z); o.w = fmaf(m, sp.w, vv.w);
            ((float4*)vout)[i] = o;
        }
    } else {
        int e = (bid - ABLK) * 256 + tid;
        float pv = ybuf[e];
        ybuf[e]  = fabsf(pv) * invS;
        yhard[e] = (pv < 0.f) ? 1.f : 0.f;
    }
}

extern "C" void kernel_launch(void* const* d_in, const int* in_sizes, int n_in,
                              void* d_out, int out_size, void* d_ws, size_t ws_size,
                              hipStream_t stream) {
    (void)in_sizes; (void)n_in; (void)out_size; (void)ws_size;
    const float* x   = (const float*)d_in[0];
    const float* v   = (const float*)d_in[1];
    const int*   cei = (const int*)d_in[2];
    const float* Wp  = (const float*)d_in[3];
    const float* bp  = (const float*)d_in[4];
    const float* Wv  = (const float*)d_in[5];
    const float* bv  = (const float*)d_in[6];
    const float* Wm1 = (const float*)d_in[7];
    const float* bm1 = (const float*)d_in[8];
    const float* Wm2 = (const float*)d_in[9];
    const float* bm2 = (const float*)d_in[10];
    const float* th  = (const float*)d_in[11];
    const float* gum = (const float*)d_in[12];

    float* out   = (float*)d_out;
    float* vout  = out;                          // [NV*H] sump until k_out
    float* maskp = out + (size_t)NVOX * H;       // [NV]
    float* ybuf  = maskp + NVOX;                 // [E]  +-p until k_out
    float* yhard = ybuf + NEDGE;                 // [E]  scratch until k_out
    float* xp    = yhard;                        // 65536 floats (256 KB)
    h16*   WvThi = (h16*)(yhard + 65536);        // 16384 h16
    h16*   WvTlo = WvThi + 16384;
    h16*   Wm1T  = WvThi + 32768;
    h16*   xh    = WvThi + 49152;                // 65536 h16 (128 KB)
    float* partial = (float*)d_ws;               // NBLK floats (~6.3 KB)

    k_pre<<<NP + 192, 256, 0, stream>>>(x, Wp, bp, Wv, Wm1, xp, WvThi, WvTlo,
                                        Wm1T, xh);
    k_mainX<<<NBLK, 256, 0, stream>>>(v, xh, bv, bm1, Wm2, bm2, WvThi, WvTlo,
                                      Wm1T, xp, cei, th, gum, maskp, ybuf, vout,
                                      partial);
    k_out<<<2 * ABLK, 256, 0, stream>>>(v, maskp, partial, vout, ybuf, yhard);
}

// Round 9
// 177.685 us; speedup vs baseline: 1.1028x; 1.0060x over previous
//
#include <hip/hip_runtime.h>

#define H     128
#define NP    512
#define NVOX  50000
#define NEDGE 800000
#define EPV   16
#define SLOPE 0.01f
#define GR    32                          // voxel rows per k_mainX block
#define NBLK  1563                        // ceil(NVOX/GR)
#define STRH  136                         // padded f16 LDS stride (halves)
#define VSTR  132                         // padded f32 LDS stride (floats)
#define C1    2.8853900817779268f         // 2*log2(e)
#define LOG2E 1.4426950408889634f
#define ABLK  3125                        // k_out part-A blocks

#define EXP2(x) __builtin_amdgcn_exp2f(x)
#define LOG2(x) __builtin_amdgcn_logf(x)
#define RCP(x)  __builtin_amdgcn_rcpf(x)

typedef _Float16 h16;
typedef __attribute__((ext_vector_type(4))) _Float16 h16x4;
typedef __attribute__((ext_vector_type(8))) _Float16 h16x8;
typedef __attribute__((ext_vector_type(4))) float    f32x4;

// DPP butterfly add: 0xB1=quad_perm[1,0,3,2] (xor1), 0x4E=quad_perm[2,3,0,1]
// (xor2), 0x141=row_half_mirror (xor4 once quads uniform). Pure VALU.
template <int CTRL>
__device__ __forceinline__ float dpp_add(float x) {
    union { float f; int i; } u, r;
    u.f = x;
    r.i = __builtin_amdgcn_update_dpp(0, u.i, CTRL, 0xf, 0xf, true);
    return x + r.f;
}

// ==== blocks [0,NP): xp' = (x@Wp+bp)*C1 ; [NP,NP+128): W split ;
//      [NP+128,NP+192): xh = f16(x) ====
__global__ __launch_bounds__(256) void k_pre(const float* __restrict__ x,
                                             const float* __restrict__ Wp,
                                             const float* __restrict__ bp,
                                             const float* __restrict__ Wv,
                                             const float* __restrict__ Wm1,
                                             float* __restrict__ xpout,
                                             h16* __restrict__ WvThi,
                                             h16* __restrict__ WvTlo,
                                             h16* __restrict__ Wm1T,
                                             h16* __restrict__ xh) {
    __shared__ float part[H];
    int bid = blockIdx.x;
    int tid = threadIdx.x;
    if (bid < NP) {
        int row = bid;
        int col = tid & 127;
        int kh  = tid >> 7;
        int kbase = kh * 64;
        const float* xr = x + (size_t)row * H;
        float acc = 0.f;
#pragma unroll 8
        for (int k = 0; k < 64; ++k)
            acc = fmaf(xr[kbase + k], Wp[(size_t)(kbase + k) * H + col], acc);
        if (kh == 1) part[col] = acc;
        __syncthreads();
        if (kh == 0) xpout[(size_t)row * H + col] = (acc + part[col] + bp[col]) * C1;
    } else if (bid < NP + 128) {
        int idx = (bid - NP) * 256 + tid;
        if (idx < 16384) {
            int k = idx >> 7, n = idx & 127;
            float w = Wv[idx];
            h16 hi = (h16)w;
            WvThi[n * H + k] = hi;
            WvTlo[n * H + k] = (h16)(w - (float)hi);
        } else {
            int j = idx - 16384;
            int k = j >> 7, n = j & 127;
            Wm1T[n * H + k] = (h16)Wm1[j];
        }
    } else {
        // f16 copy of x: 64 blocks x 256 threads x 4 elems = 65536
        int f4 = (bid - NP - 128) * 256 + tid;
        float4 val = *(const float4*)&x[(size_t)f4 * 4];
        h16x4 hv;
        hv.x = (h16)val.x; hv.y = (h16)val.y;
        hv.z = (h16)val.z; hv.w = (h16)val.w;
        *(h16x4*)&xh[(size_t)f4 * 4] = hv;
    }
}

// ======= fused: vv GEMM (LDS-only), mask, per-edge p, sump, psum partial ====
// ROUND 9: request-rate theory. Across every null experiment (bytes, layout,
// occupancy, pipeline depth) the constant was 8 gather REQUESTS per edge
// (xp 4x128B + x 4x64B h16x4 segments) = ~1.4 req/cy/CU, a TA ceiling.
// Change: read the f16 x row as 2x h16x8 (16B/lane, 8 lanes = 128B = one
// full-line request) -> 6 requests/edge. Column mapping for x moves to
// {lk*8, 64+lk*8}; xp/th2 mapping untouched; per-column t-order identical
// -> outputs bit-identical (absmax canary 0.00390625).
__global__ __launch_bounds__(256, 4) void k_mainX(
    const float* __restrict__ v,   const h16* __restrict__ xh,
    const float* __restrict__ bv,  const float* __restrict__ bm1,
    const float* __restrict__ Wm2, const float* __restrict__ bm2,
    const h16* __restrict__ WvThi, const h16* __restrict__ WvTlo,
    const h16* __restrict__ Wm1T,
    const float* __restrict__ xp,  const int* __restrict__ cei,
    const float* __restrict__ theta, const float* __restrict__ gum,
    float* __restrict__ mask_out, float* __restrict__ pout,
    float* __restrict__ sump,     float* __restrict__ partial)
{
    __shared__ __align__(16) char ldsbuf[2 * GR * STRH * 2];  // 17408 B
    h16*   vh = (h16*)ldsbuf;            // [GR][STRH]
    h16*   vl = vh + GR * STRH;
    float* vt = (float*)ldsbuf;          // [GR][VSTR] f32 vv tile (reuse)
    __shared__ int   ceit[EPV * GR];     // [t*GR+c]
    __shared__ float gumt[EPV * GR];     // pre-transformed: exp(gumbel)
    __shared__ float pmbuf[4][GR];
    __shared__ float psums[4];

    int tid  = threadIdx.x;
    int base = blockIdx.x * GR;

    // ---- stage v tile (f16 hi/lo split) + cei/gum tiles (clamped tail) ----
#pragma unroll
    for (int i = 0; i < 4; ++i) {
        int f  = i * 256 + tid;          // 1024 float4 slots
        int r  = f >> 5, c4 = f & 31;
        int gr = base + r; if (gr >= NVOX) gr = NVOX - 1;
        float4 val = *(const float4*)&v[(size_t)gr * H + c4 * 4];
        h16x4 hi, lo;
        hi.x = (h16)val.x; lo.x = (h16)(val.x - (float)hi.x);
        hi.y = (h16)val.y; lo.y = (h16)(val.y - (float)hi.y);
        hi.z = (h16)val.z; lo.z = (h16)(val.z - (float)hi.z);
        hi.w = (h16)val.w; lo.w = (h16)(val.w - (float)hi.w);
        *(h16x4*)&vh[r * STRH + c4 * 4] = hi;
        *(h16x4*)&vl[r * STRH + c4 * 4] = lo;
    }
#pragma unroll
    for (int it = 0; it < 2; ++it) {
        int idx = it * 256 + tid;        // 512 slots
        int t = idx >> 5, c = idx & 31;
        int vx = base + c; if (vx >= NVOX) vx = NVOX - 1;
        int e = vx + t * NVOX;
        ceit[idx] = cei[e];
        gumt[idx] = -LOG2E * RCP(LOG2(gum[e]));   // exp(gumbel) hoisted
    }
    __syncthreads();

    // ---- dual GEMM via MFMA 16x16x32 f16 (split hi/lo for Wv) ----
    int wave = tid >> 6, lane = tid & 63;
    int m16 = lane & 15, quad = lane >> 4;
    int cb = wave * 32;

    f32x4 aV[2][2], aM[2][2];
#pragma unroll
    for (int rt = 0; rt < 2; ++rt)
#pragma unroll
        for (int ct = 0; ct < 2; ++ct) { aV[rt][ct] = (f32x4)0.f; aM[rt][ct] = (f32x4)0.f; }

#pragma unroll
    for (int kc = 0; kc < 4; ++kc) {
        int kofs = kc * 32 + quad * 8;
        h16x8 ah[2], al[2];
#pragma unroll
        for (int rt = 0; rt < 2; ++rt) {
            int row = rt * 16 + m16;
            ah[rt] = *(const h16x8*)&vh[row * STRH + kofs];
            al[rt] = *(const h16x8*)&vl[row * STRH + kofs];
        }
#pragma unroll
        for (int ct = 0; ct < 2; ++ct) {
            int n = cb + ct * 16 + m16;
            h16x8 bh = *(const h16x8*)&WvThi[n * H + kofs];
            h16x8 bl = *(const h16x8*)&WvTlo[n * H + kofs];
            h16x8 bm = *(const h16x8*)&Wm1T[n * H + kofs];
#pragma unroll
            for (int rt = 0; rt < 2; ++rt) {
                aV[rt][ct] = __builtin_amdgcn_mfma_f32_16x16x32_f16(ah[rt], bh, aV[rt][ct], 0, 0, 0);
                aV[rt][ct] = __builtin_amdgcn_mfma_f32_16x16x32_f16(al[rt], bh, aV[rt][ct], 0, 0, 0);
                aV[rt][ct] = __builtin_amdgcn_mfma_f32_16x16x32_f16(ah[rt], bl, aV[rt][ct], 0, 0, 0);
                aM[rt][ct] = __builtin_amdgcn_mfma_f32_16x16x32_f16(ah[rt], bm, aM[rt][ct], 0, 0, 0);
            }
        }
    }
    __syncthreads();                     // vh/vl fully consumed

    // ---- write vv tile (prescaled by C1) to LDS + mask partials ----
    float pml[2][4];
#pragma unroll
    for (int rt = 0; rt < 2; ++rt)
#pragma unroll
        for (int reg = 0; reg < 4; ++reg) pml[rt][reg] = 0.f;
#pragma unroll
    for (int ct = 0; ct < 2; ++ct) {
        int col = cb + ct * 16 + m16;
        float bvc = bv[col], bmc = bm1[col], w2c = Wm2[col];
#pragma unroll
        for (int rt = 0; rt < 2; ++rt)
#pragma unroll
            for (int reg = 0; reg < 4; ++reg) {
                int row = rt * 16 + quad * 4 + reg;
                vt[row * VSTR + col] = (aV[rt][ct][reg] + bvc) * C1;
                float m = aM[rt][ct][reg] + bmc;
                m = (m >= 0.f) ? m : SLOPE * m;
                pml[rt][reg] = fmaf(m, w2c, pml[rt][reg]);
            }
    }
#pragma unroll
    for (int rt = 0; rt < 2; ++rt)
#pragma unroll
        for (int reg = 0; reg < 4; ++reg) {  // sum over m16 (16 lanes), VALU DPP
            pml[rt][reg] = dpp_add<0xB1>(pml[rt][reg]);
            pml[rt][reg] = dpp_add<0x4E>(pml[rt][reg]);
            pml[rt][reg] = dpp_add<0x141>(pml[rt][reg]);
            pml[rt][reg] = dpp_add<0x140>(pml[rt][reg]);
        }
    if (m16 == 0) {
#pragma unroll
        for (int rt = 0; rt < 2; ++rt)
#pragma unroll
            for (int reg = 0; reg < 4; ++reg)
                pmbuf[wave][rt * 16 + quad * 4 + reg] = pml[rt][reg];
    }
    __syncthreads();                     // vt + pmbuf visible
    if (wave == 0 && lane < GR) {
        int gr = base + lane;
        if (gr < NVOX) {
            float s = pmbuf[0][lane] + pmbuf[1][lane] + pmbuf[2][lane]
                    + pmbuf[3][lane] + bm2[0];
            mask_out[gr] = RCP(1.f + EXP2(-s * LOG2E));
        }
    }

    // ---- edges: 8 lanes/edge, group g owns voxel base+g ----
    int g = tid >> 3, lk = tid & 7;
    int vox = base + g;
    bool valid = vox < NVOX;
    float th2[16], thsum = 0.f;
#pragma unroll
    for (int i = 0; i < 4; ++i) {
        float4 t4 = *(const float4*)&theta[(lk + 8 * i) * 4];
        th2[i * 4 + 0] = -2.f * LOG2E * t4.x; th2[i * 4 + 1] = -2.f * LOG2E * t4.y;
        th2[i * 4 + 2] = -2.f * LOG2E * t4.z; th2[i * 4 + 3] = -2.f * LOG2E * t4.w;
        thsum += LOG2E * (t4.x + t4.y + t4.z + t4.w);
    }
    const float* vr = &vt[g * VSTR];
    float4 b0 = *(const float4*)&vr[(lk +  0) * 4];
    float4 b1 = *(const float4*)&vr[(lk +  8) * 4];
    float4 b2 = *(const float4*)&vr[(lk + 16) * 4];
    float4 b3 = *(const float4*)&vr[(lk + 24) * 4];

    // x-columns per lane: {lk*8..lk*8+8} and {64+lk*8..64+lk*8+8}
    float4 s0a = make_float4(0.f,0.f,0.f,0.f), s0b = s0a, s1a = s0a, s1b = s0a;
    float psum = 0.f, pmax = -1.f;
    int   pidx = 0;

    // prologue: load xp row (4x128B req) + x row (2x128B req) for t=0
    int src0 = ceit[g];
    const float4* r0 = (const float4*)(xp + (size_t)src0 * H);
    float4 a0 = r0[lk], a1 = r0[lk + 8], a2 = r0[lk + 16], a3 = r0[lk + 24];
    const h16x8* q0 = (const h16x8*)(xh + (size_t)src0 * H);
    h16x8 c0 = q0[lk], c1 = q0[lk + 8];

    for (int t = 0; t < EPV; ++t) {
        // issue NEXT generation first (consumed one iteration later)
        float4 n0, n1, n2, n3;
        h16x8 d0, d1;
        int srcN;
        if (t < EPV - 1) {
            srcN = ceit[(t + 1) * GR + g];
            const float4* rN = (const float4*)(xp + (size_t)srcN * H);
            n0 = rN[lk]; n1 = rN[lk + 8]; n2 = rN[lk + 16]; n3 = rN[lk + 24];
            const h16x8* qN = (const h16x8*)(xh + (size_t)srcN * H);
            d0 = qN[lk]; d1 = qN[lk + 8];
        } else {
            srcN = src0; n0 = a0; n1 = a1; n2 = a2; n3 = a3;
            d0 = c0; d1 = c1;
        }
        float wvt = gumt[t * GR + g];    // exp(gumbel), pre-transformed

        float acc0 = thsum, acc1 = 0.f;
        acc0 = fmaf(th2[ 0], RCP(EXP2(a0.x + b0.x) + 1.f), acc0);
        acc1 = fmaf(th2[ 1], RCP(EXP2(a0.y + b0.y) + 1.f), acc1);
        acc0 = fmaf(th2[ 2], RCP(EXP2(a0.z + b0.z) + 1.f), acc0);
        acc1 = fmaf(th2[ 3], RCP(EXP2(a0.w + b0.w) + 1.f), acc1);
        acc0 = fmaf(th2[ 4], RCP(EXP2(a1.x + b1.x) + 1.f), acc0);
        acc1 = fmaf(th2[ 5], RCP(EXP2(a1.y + b1.y) + 1.f), acc1);
        acc0 = fmaf(th2[ 6], RCP(EXP2(a1.z + b1.z) + 1.f), acc0);
        acc1 = fmaf(th2[ 7], RCP(EXP2(a1.w + b1.w) + 1.f), acc1);
        acc0 = fmaf(th2[ 8], RCP(EXP2(a2.x + b2.x) + 1.f), acc0);
        acc1 = fmaf(th2[ 9], RCP(EXP2(a2.y + b2.y) + 1.f), acc1);
        acc0 = fmaf(th2[10], RCP(EXP2(a2.z + b2.z) + 1.f), acc0);
        acc1 = fmaf(th2[11], RCP(EXP2(a2.w + b2.w) + 1.f), acc1);
        acc0 = fmaf(th2[12], RCP(EXP2(a3.x + b3.x) + 1.f), acc0);
        acc1 = fmaf(th2[13], RCP(EXP2(a3.y + b3.y) + 1.f), acc1);
        acc0 = fmaf(th2[14], RCP(EXP2(a3.z + b3.z) + 1.f), acc0);
        acc1 = fmaf(th2[15], RCP(EXP2(a3.w + b3.w) + 1.f), acc1);
        float acc = acc0 + acc1;
        // 8-lane butterfly in VALU (DPP)
        acc = dpp_add<0xB1>(acc);
        acc = dpp_add<0x4E>(acc);
        acc = dpp_add<0x141>(acc);       // identical across the 8 lanes
        float p = EXP2(acc) * wvt;       // exp(theta.tanh + gumbel), TAU=1
        if (p > pmax) { pmax = p; pidx = t; }   // strict > = first max
        if (valid) psum += p;
        if (lk == 0 && valid) pout[vox + t * NVOX] = p;  // argmax fixed post-loop
        // s-accum over this lane's x columns (c* loaded one iteration ago)
        s0a.x = fmaf(p, (float)c0[0], s0a.x); s0a.y = fmaf(p, (float)c0[1], s0a.y);
        s0a.z = fmaf(p, (float)c0[2], s0a.z); s0a.w = fmaf(p, (float)c0[3], s0a.w);
        s0b.x = fmaf(p, (float)c0[4], s0b.x); s0b.y = fmaf(p, (float)c0[5], s0b.y);
        s0b.z = fmaf(p, (float)c0[6], s0b.z); s0b.w = fmaf(p, (float)c0[7], s0b.w);
        s1a.x = fmaf(p, (float)c1[0], s1a.x); s1a.y = fmaf(p, (float)c1[1], s1a.y);
        s1a.z = fmaf(p, (float)c1[2], s1a.z); s1a.w = fmaf(p, (float)c1[3], s1a.w);
        s1b.x = fmaf(p, (float)c1[4], s1b.x); s1b.y = fmaf(p, (float)c1[5], s1b.y);
        s1b.z = fmaf(p, (float)c1[6], s1b.z); s1b.w = fmaf(p, (float)c1[7], s1b.w);
        a0 = n0; a1 = n1; a2 = n2; a3 = n3;
        c0 = d0; c1 = d1;
        src0 = srcN;
    }
    // same-thread same-address store after the loop's store: program order holds
    if (lk == 0 && valid) pout[vox + pidx * NVOX] = -pmax;
    if (valid) {
        float* sr = sump + (size_t)vox * H;
        *(float4*)&sr[lk * 8]          = s0a;
        *(float4*)&sr[lk * 8 + 4]      = s0b;
        *(float4*)&sr[64 + lk * 8]     = s1a;
        *(float4*)&sr[64 + lk * 8 + 4] = s1b;
    }
    // wave psum: groups occupy disjoint 8-lane slots -> xor 8/16/32 sums each once
    psum += __shfl_xor(psum, 8, 64);
    psum += __shfl_xor(psum, 16, 64);
    psum += __shfl_xor(psum, 32, 64);
    if (lane == 0) psums[wave] = psum;
    __syncthreads();                     // psums visible
    if (tid == 0)
        partial[blockIdx.x] = psums[0] + psums[1] + psums[2] + psums[3];
}

// ---- finalize: per-block redundant invS (1563 partials, L2-resident) + stream ----
// blocks [0,ABLK): vout = v + mask*invS*sump ; blocks [ABLK,2*ABLK): y, y_hard
__global__ __launch_bounds__(256) void k_out(const float* __restrict__ v,
                                             const float* __restrict__ maskp,
                                             const float* __restrict__ partial,
                                             float* __restrict__ vout,  // sump in
                                             float* __restrict__ ybuf,  // +-p in
                                             float* __restrict__ yhard) {
    __shared__ float wsum[4];
    int tid = threadIdx.x;
    float s = 0.f;
    for (int i = tid; i < NBLK; i += 256) s += partial[i];
#pragma unroll
    for (int off = 32; off >= 1; off >>= 1) s += __shfl_xor(s, off, 64);
    if ((tid & 63) == 0) wsum[tid >> 6] = s;
    __syncthreads();
    float invS = RCP(wsum[0] + wsum[1] + wsum[2] + wsum[3]);  // identical per block

    int bid = blockIdx.x;
    if (bid < ABLK) {
#pragma unroll
        for (int r = 0; r < 2; ++r) {
            int i = (bid + r * ABLK) * 256 + tid;
            float4 sp = ((const float4*)vout)[i];
            float4 vv = ((const float4*)v)[i];
            float  m  = maskp[i >> 5] * invS;
            float4 o;
            o.x = fmaf(m, sp.x, vv.x); o.y = fmaf(m, sp.y, vv.y);
            o.z = fmaf(m, sp.z, vv.z); o.w = fmaf(m, sp.w, vv.w);
            ((float4*)vout)[i] = o;
        }
    } else {
        int e = (bid - ABLK) * 256 + tid;
        float pv = ybuf[e];
        ybuf[e]  = fabsf(pv) * invS;
        yhard[e] = (pv < 0.f) ? 1.f : 0.f;
    }
}

extern "C" void kernel_launch(void* const* d_in, const int* in_sizes, int n_in,
                              void* d_out, int out_size, void* d_ws, size_t ws_size,
                              hipStream_t stream) {
    (void)in_sizes; (void)n_in; (void)out_size; (void)ws_size;
    const float* x   = (const float*)d_in[0];
    const float* v   = (const float*)d_in[1];
    const int*   cei = (const int*)d_in[2];
    const float* Wp  = (const float*)d_in[3];
    const float* bp  = (const float*)d_in[4];
    const float* Wv  = (const float*)d_in[5];
    const float* bv  = (const float*)d_in[6];
    const float* Wm1 = (const float*)d_in[7];
    const float* bm1 = (const float*)d_in[8];
    const float* Wm2 = (const float*)d_in[9];
    const float* bm2 = (const float*)d_in[10];
    const float* th  = (const float*)d_in[11];
    const float* gum = (const float*)d_in[12];

    float* out   = (float*)d_out;
    float* vout  = out;                          // [NV*H] sump until k_out
    float* maskp = out + (size_t)NVOX * H;       // [NV]
    float* ybuf  = maskp + NVOX;                 // [E]  +-p until k_out
    float* yhard = ybuf + NEDGE;                 // [E]  scratch until k_out
    float* xp    = yhard;                        // 65536 floats (256 KB)
    h16*   WvThi = (h16*)(yhard + 65536);        // 16384 h16
    h16*   WvTlo = WvThi + 16384;
    h16*   Wm1T  = WvThi + 32768;
    h16*   xh    = WvThi + 49152;                // 65536 h16 (128 KB)
    float* partial = (float*)d_ws;               // NBLK floats (~6.3 KB)

    k_pre<<<NP + 192, 256, 0, stream>>>(x, Wp, bp, Wv, Wm1, xp, WvThi, WvTlo,
                                        Wm1T, xh);
    k_mainX<<<NBLK, 256, 0, stream>>>(v, xh, bv, bm1, Wm2, bm2, WvThi, WvTlo,
                                      Wm1T, xp, cei, th, gum, maskp, ybuf, vout,
                                      partial);
    k_out<<<2 * ABLK, 256, 0, stream>>>(v, maskp, partial, vout, ybuf, yhard);
}